// Round 10
// baseline (104.075 us; speedup 1.0000x reference)
//
#include <hip/hip_runtime.h>
#include <hip/hip_bf16.h>
#include <math.h>

// Problem constants (match reference)
#define NB 8
#define NP 512
#define NL 64
#define NH 128
#define NRB 32
#define NPT 20
#define NLT 16
#define PAIRS_CAP (NP * NL)      // 32768 pairs per complex max
#define CHUNKS 512               // PAIRS_CAP / 64
#define K1 96                    // extended layer-1 K: 32 rb + 20 pt + 16 lt + pad

typedef __attribute__((ext_vector_type(8))) _Float16 h8;
typedef __attribute__((ext_vector_type(4))) float f4;

// ---------------------------------------------------------------------------
// Kernel A: fused prep (unchanged from R9).
//  blk 0..7: compaction -> packed records {dist,(pt<<16)|lt}; blk 8: zero acc;
//  blk 9..104: wt1e col k; blk 105..232: wt2t/wt3t transpose row k.
// ---------------------------------------------------------------------------
__global__ __launch_bounds__(256) void prep(
    const float* __restrict__ ppos, const float* __restrict__ lpos,
    const int* __restrict__ ptype_g, const int* __restrict__ ltype_g,
    const float* __restrict__ pemb, const float* __restrict__ lemb,
    const float* __restrict__ W1, const float* __restrict__ b1,
    const float* __restrict__ W2, const float* __restrict__ W3,
    uint2* __restrict__ rec, unsigned* __restrict__ cnt,
    _Float16* __restrict__ wt1e, _Float16* __restrict__ wt2t,
    _Float16* __restrict__ wt3t, float* __restrict__ acc)
{
  int blk = blockIdx.x, tid = threadIdx.x;

  if (blk < 8) {
    int b = blk;
    int w = tid >> 6, lane = tid & 63;
    __shared__ float slig[NL * 3];
    __shared__ int slt[NL];
    __shared__ unsigned wtot[4];

    if (tid < NL * 3) slig[tid] = lpos[b * NL * 3 + tid];
    if (tid < NL) slt[tid] = ltype_g[b * NL + tid];
    __syncthreads();

    const float* pp = ppos + (size_t)(b * NP + 2 * tid) * 3;
    float p0x = pp[0], p0y = pp[1], p0z = pp[2];
    float p1x = pp[3], p1y = pp[4], p1z = pp[5];
    unsigned pt0 = (unsigned)ptype_g[b * NP + 2 * tid];
    unsigned pt1 = (unsigned)ptype_g[b * NP + 2 * tid + 1];

    unsigned long long m0 = 0ull, m1 = 0ull;
    for (int l = 0; l < NL; ++l) {
      float qx = slig[3 * l + 0], qy = slig[3 * l + 1], qz = slig[3 * l + 2];
      float dx0 = p0x - qx, dy0 = p0y - qy, dz0 = p0z - qz;
      float dx1 = p1x - qx, dy1 = p1y - qy, dz1 = p1z - qz;
      bool v0 = sqrtf(dx0 * dx0 + dy0 * dy0 + dz0 * dz0) < 8.0f;
      bool v1 = sqrtf(dx1 * dx1 + dy1 * dy1 + dz1 * dz1) < 8.0f;
      m0 |= ((unsigned long long)v0) << l;
      m1 |= ((unsigned long long)v1) << l;
    }
    unsigned count = (unsigned)(__popcll(m0) + __popcll(m1));

    unsigned inc = count;
    #pragma unroll
    for (int d = 1; d < 64; d <<= 1) {
      unsigned v = __shfl_up(inc, d);
      if (lane >= d) inc += v;
    }
    if (lane == 63) wtot[w] = inc;
    __syncthreads();
    unsigned wbase = 0;
    for (int i = 0; i < w; ++i) wbase += wtot[i];
    unsigned base = wbase + inc - count;          // exclusive prefix
    if (tid == 255) cnt[b] = wbase + inc;

    uint2* dst = rec + (size_t)b * PAIRS_CAP;
    unsigned long long mm = m0;
    while (mm) {
      int l = __builtin_ctzll(mm); mm &= mm - 1ull;
      float dx = p0x - slig[3 * l], dy = p0y - slig[3 * l + 1], dz = p0z - slig[3 * l + 2];
      float d = sqrtf(dx * dx + dy * dy + dz * dz);
      dst[base++] = (uint2){__float_as_uint(d), (pt0 << 16) | (unsigned)slt[l]};
    }
    mm = m1;
    while (mm) {
      int l = __builtin_ctzll(mm); mm &= mm - 1ull;
      float dx = p1x - slig[3 * l], dy = p1y - slig[3 * l + 1], dz = p1z - slig[3 * l + 2];
      float d = sqrtf(dx * dx + dy * dy + dz * dz);
      dst[base++] = (uint2){__float_as_uint(d), (pt1 << 16) | (unsigned)slt[l]};
    }
    return;
  }

  if (blk == 8) {
    for (int i = tid; i < NB * NH; i += 256) acc[i] = 0.0f;
    return;
  }

  if (blk < 105) {
    int k = blk - 9;
    if (tid >= NH) return;
    int c = tid;
    float v;
    if (k < 32) {
      v = W1[(2 * NH + k) * NH + c];
    } else if (k < 52) {
      int t = k - 32;
      float s = b1[c];
      for (int j = 0; j < NH; ++j)
        s = fmaf(pemb[t * NH + j], W1[j * NH + c], s);
      v = s;
    } else if (k < 68) {
      int t = k - 52;
      float s = 0.0f;
      for (int j = 0; j < NH; ++j)
        s = fmaf(lemb[t * NH + j], W1[(NH + j) * NH + c], s);
      v = s;
    } else {
      v = 0.0f;
    }
    wt1e[c * K1 + k] = (_Float16)v;
    return;
  }

  {
    int k = blk - 105;
    if (tid >= NH) return;
    int c = tid;
    wt2t[c * NH + k] = (_Float16)W2[k * NH + c];
    wt3t[c * NH + k] = (_Float16)W3[k * NH + c];
    return;
  }
}

// ---------------------------------------------------------------------------
// Kernel B: BARRIER-FREE wave-private MFMA pair MLP.
// Block = 64-pair chunk, 4 waves; wave w privately owns ROWS 16w..16w+15 and
// computes ALL 128 output cols for them. Layer-1 input built directly in
// registers (A-frag row = l&15 -> lane's own rb/onehot values). Inter-layer
// C->A relayout via a wave-PRIVATE 4KB LDS strip: same-wave dep, compiler
// lgkmcnt, NO __syncthreads in the layer pipeline. One final barrier for a
// cross-wave column-sum combine (cuts atomics to 128/block).
// Swizzle (row&15)<<3: rows r/r+8 no longer alias banks on epilogue writes.
// C/D layout per m89: row = 4*(l>>4)+reg, col = 16n + (l&15).
// ---------------------------------------------------------------------------
__device__ __forceinline__ int swz(int row, int col) {
  return row * NH + (col ^ ((row & 15) << 3));   // half-index swizzle
}

__global__ __launch_bounds__(256, 4) void pair_mlp(
    const _Float16* __restrict__ wt1e, const _Float16* __restrict__ wt2t,
    const _Float16* __restrict__ wt3t,
    const float* __restrict__ b2, const float* __restrict__ b3,
    const uint2* __restrict__ rec, const unsigned* __restrict__ cnt,
    float* __restrict__ accum)
{
  __shared__ _Float16 sS[NL * NH];   // 16 KB; wave w owns rows 16w..16w+15
  __shared__ float comb[4 * NH];     // 2 KB cross-wave combine

  int tid = threadIdx.x;
  int w  = __builtin_amdgcn_readfirstlane(tid >> 6);
  int l  = tid & 63;
  int b     = blockIdx.x & 7;
  int chunk = blockIdx.x >> 3;

  unsigned total = cnt[b];
  if ((unsigned)(chunk * 64) >= total) return;

  int c16  = l & 15;                 // frag col selector == strip row selector
  int g    = l >> 4;                 // k-subgroup (8-half block)
  int row0 = 16 * w;                 // wave's private strip base

  // --- one coalesced 8B record load: this lane's A-row is row0 + c16 -------
  int idx = chunk * 64 + row0 + c16;
  int src = ((unsigned)idx < total) ? idx : 0;    // duplicate row 0 in tail
  uint2 rcd = rec[(size_t)b * PAIRS_CAP + src];
  float dist = __uint_as_float(rcd.x);
  int pt = (int)(rcd.y >> 16), lt = (int)(rcd.y & 0xffffu);

  const float stepc = 8.0f / 31.0f;
  const float invw = 1.0f / (0.125f + 1e-8f);

  // --- build layer-1 A-frags in registers (no LDS, no barrier) -------------
  // kk=0: c=8g+j in [0,32): rb.  kk=1: c-32=u: pt 1hot (u<20) | lt 1hot.
  // kk=2: c-64=u: lt 1hot (u<4, idx 12+u) | zero.
  h8 a1k0, a1k1, a1k2;
  #pragma unroll
  for (int j = 0; j < 8; ++j) {
    int u = 8 * g + j;
    float t = (dist - stepc * (float)u) * invw;
    a1k0[j] = (_Float16)__expf(-0.5f * t * t);
    a1k1[j] = (_Float16)((u < 20) ? ((u == pt) ? 1.0f : 0.0f)
                                  : ((u - 20 == lt) ? 1.0f : 0.0f));
    a1k2[j] = (_Float16)(((u < 4) && (u + 12 == lt)) ? 1.0f : 0.0f);
  }

  // --- layer 1: K=96, 8 n-frags x 3 kk = 24 MFMA ---------------------------
  f4 acc[8];
  #pragma unroll
  for (int nn = 0; nn < 8; ++nn) acc[nn] = (f4){0.0f, 0.0f, 0.0f, 0.0f};
  #pragma unroll
  for (int nn = 0; nn < 8; ++nn) {
    const _Float16* wp = &wt1e[(16 * nn + c16) * K1 + 8 * g];
    h8 bf0 = *(const h8*)&wp[0];
    h8 bf1 = *(const h8*)&wp[32];
    h8 bf2 = *(const h8*)&wp[64];
    acc[nn] = __builtin_amdgcn_mfma_f32_16x16x32_f16(a1k0, bf0, acc[nn], 0, 0, 0);
    acc[nn] = __builtin_amdgcn_mfma_f32_16x16x32_f16(a1k1, bf1, acc[nn], 0, 0, 0);
    acc[nn] = __builtin_amdgcn_mfma_f32_16x16x32_f16(a1k2, bf2, acc[nn], 0, 0, 0);
  }
  #pragma unroll
  for (int nn = 0; nn < 8; ++nn)
    #pragma unroll
    for (int r = 0; r < 4; ++r)
      sS[swz(row0 + 4 * g + r, 16 * nn + c16)] = (_Float16)fmaxf(acc[nn][r], 0.0f);

  // --- layer 2: K=128, reads own strip (same-wave dep, no barrier) ---------
  {
    h8 a0 = *(const h8*)&sS[swz(row0 + c16, 8 * g)];
    h8 a1 = *(const h8*)&sS[swz(row0 + c16, 32 + 8 * g)];
    h8 a2 = *(const h8*)&sS[swz(row0 + c16, 64 + 8 * g)];
    h8 a3 = *(const h8*)&sS[swz(row0 + c16, 96 + 8 * g)];
    f4 acc2[8];
    #pragma unroll
    for (int nn = 0; nn < 8; ++nn) {
      float bb = b2[16 * nn + c16];
      acc2[nn] = (f4){bb, bb, bb, bb};
    }
    #pragma unroll
    for (int nn = 0; nn < 8; ++nn) {
      const _Float16* wp = &wt2t[(16 * nn + c16) * NH + 8 * g];
      h8 bf0 = *(const h8*)&wp[0];
      h8 bf1 = *(const h8*)&wp[32];
      h8 bf2 = *(const h8*)&wp[64];
      h8 bf3 = *(const h8*)&wp[96];
      acc2[nn] = __builtin_amdgcn_mfma_f32_16x16x32_f16(a0, bf0, acc2[nn], 0, 0, 0);
      acc2[nn] = __builtin_amdgcn_mfma_f32_16x16x32_f16(a1, bf1, acc2[nn], 0, 0, 0);
      acc2[nn] = __builtin_amdgcn_mfma_f32_16x16x32_f16(a2, bf2, acc2[nn], 0, 0, 0);
      acc2[nn] = __builtin_amdgcn_mfma_f32_16x16x32_f16(a3, bf3, acc2[nn], 0, 0, 0);
    }
    #pragma unroll
    for (int nn = 0; nn < 8; ++nn)
      #pragma unroll
      for (int r = 0; r < 4; ++r)
        sS[swz(row0 + 4 * g + r, 16 * nn + c16)] = (_Float16)fmaxf(acc2[nn][r], 0.0f);
  }

  // --- layer 3: K=128 + masked column-sum ----------------------------------
  float cs[8];
  {
    h8 a0 = *(const h8*)&sS[swz(row0 + c16, 8 * g)];
    h8 a1 = *(const h8*)&sS[swz(row0 + c16, 32 + 8 * g)];
    h8 a2 = *(const h8*)&sS[swz(row0 + c16, 64 + 8 * g)];
    h8 a3 = *(const h8*)&sS[swz(row0 + c16, 96 + 8 * g)];
    f4 acc3[8];
    #pragma unroll
    for (int nn = 0; nn < 8; ++nn) {
      float bb = b3[16 * nn + c16];
      acc3[nn] = (f4){bb, bb, bb, bb};
    }
    #pragma unroll
    for (int nn = 0; nn < 8; ++nn) {
      const _Float16* wp = &wt3t[(16 * nn + c16) * NH + 8 * g];
      h8 bf0 = *(const h8*)&wp[0];
      h8 bf1 = *(const h8*)&wp[32];
      h8 bf2 = *(const h8*)&wp[64];
      h8 bf3 = *(const h8*)&wp[96];
      acc3[nn] = __builtin_amdgcn_mfma_f32_16x16x32_f16(a0, bf0, acc3[nn], 0, 0, 0);
      acc3[nn] = __builtin_amdgcn_mfma_f32_16x16x32_f16(a1, bf1, acc3[nn], 0, 0, 0);
      acc3[nn] = __builtin_amdgcn_mfma_f32_16x16x32_f16(a2, bf2, acc3[nn], 0, 0, 0);
      acc3[nn] = __builtin_amdgcn_mfma_f32_16x16x32_f16(a3, bf3, acc3[nn], 0, 0, 0);
    }
    int rem = (int)total - chunk * 64;              // rows < rem are valid
    #pragma unroll
    for (int nn = 0; nn < 8; ++nn) {
      float s = 0.0f;
      #pragma unroll
      for (int r = 0; r < 4; ++r) {
        bool ok = (row0 + 4 * g + r) < rem;
        s += ok ? fmaxf(acc3[nn][r], 0.0f) : 0.0f;
      }
      s += __shfl_xor(s, 16);                       // sum the 4 row-groups
      s += __shfl_xor(s, 32);
      cs[nn] = s;                                   // col 16nn+c16, all lanes
    }
  }

  // --- cross-wave combine (the only barrier) + 128 atomics/block -----------
  if (g == 0) {
    #pragma unroll
    for (int nn = 0; nn < 8; ++nn)
      comb[w * NH + 16 * nn + c16] = cs[nn];
  }
  __syncthreads();
  if (tid < NH) {
    float s = comb[tid] + comb[NH + tid] + comb[2 * NH + tid] + comb[3 * NH + tid];
    atomicAdd(&accum[b * NH + tid], s);
  }
}

// ---------------------------------------------------------------------------
// Kernel C: scoring head (unchanged from R9).
// ---------------------------------------------------------------------------
__global__ __launch_bounds__(128) void score_head(
    const float* __restrict__ acc, const unsigned* __restrict__ cnt,
    const float* __restrict__ Wr1, const float* __restrict__ br1,
    const float* __restrict__ Wr2, const float* __restrict__ br2,
    float* __restrict__ out)
{
  int b = blockIdx.x;
  int tid = threadIdx.x;
  __shared__ float sr[NH];
  __shared__ float wsum[2];
  unsigned c = cnt[b];
  float denom = fmaxf((float)c, 1.0f);
  sr[tid] = acc[b * NH + tid] / denom;
  __syncthreads();
  float s = br1[tid];
  for (int k = 0; k < NH; ++k)
    s = fmaf(sr[k], Wr1[k * NH + tid], s);
  float v = fmaxf(s, 0.0f) * Wr2[tid];
  #pragma unroll
  for (int d = 1; d < 64; d <<= 1) v += __shfl_xor(v, d);
  if ((tid & 63) == 0) wsum[tid >> 6] = v;
  __syncthreads();
  if (tid == 0)
    out[b] = (c > 0) ? (wsum[0] + wsum[1] + br2[0]) : 0.0f;
}

// ---------------------------------------------------------------------------
extern "C" void kernel_launch(void* const* d_in, const int* in_sizes, int n_in,
                              void* d_out, int out_size, void* d_ws, size_t ws_size,
                              hipStream_t stream)
{
  const float* ppos = (const float*)d_in[0];
  const float* lpos = (const float*)d_in[1];
  const float* pemb = (const float*)d_in[2];
  const float* lemb = (const float*)d_in[3];
  const float* W1   = (const float*)d_in[4];
  const float* b1   = (const float*)d_in[5];
  const float* W2   = (const float*)d_in[6];
  const float* b2   = (const float*)d_in[7];
  const float* W3   = (const float*)d_in[8];
  const float* b3   = (const float*)d_in[9];
  const float* Wr1  = (const float*)d_in[10];
  const float* br1  = (const float*)d_in[11];
  const float* Wr2  = (const float*)d_in[12];
  const float* br2  = (const float*)d_in[13];
  const int*   ptyp = (const int*)d_in[14];
  const int*   ltyp = (const int*)d_in[15];
  // d_in[16], d_in[17] (batch indices) unused: batches contiguous & uniform.

  float* ws  = (float*)d_ws;
  float* acc = ws;                          // 1024 f
  unsigned* cnt = (unsigned*)(ws + 1024);   // 8 u32 (pad to 1032)
  uint2* rec = (uint2*)(ws + 1032);         // 8*32768*8B = 2 MB (524288 f)
  _Float16* wt1e = (_Float16*)(ws + 1032 + 524288);                // 128*96 h
  _Float16* wt2t = (_Float16*)(ws + 1032 + 524288 + 6144);         // 128*128 h
  _Float16* wt3t = (_Float16*)(ws + 1032 + 524288 + 6144 + 8192);  // 128*128 h

  prep<<<233, 256, 0, stream>>>(ppos, lpos, ptyp, ltyp, pemb, lemb,
                                W1, b1, W2, W3,
                                rec, cnt, wt1e, wt2t, wt3t, acc);
  pair_mlp<<<NB * CHUNKS, 256, 0, stream>>>(wt1e, wt2t, wt3t, b2, b3,
                                            rec, cnt, acc);
  score_head<<<NB, 128, 0, stream>>>(acc, cnt, Wr1, br1, Wr2, br2, (float*)d_out);
}

// Round 11
// 57.803 us; speedup vs baseline: 1.8005x; 1.8005x over previous
//
#include <hip/hip_runtime.h>
#include <hip/hip_bf16.h>
#include <math.h>

// Problem constants (match reference)
#define NB 8
#define NP 512
#define NL 64
#define NH 128
#define NRB 32
#define NPT 20
#define NLT 16
#define PAIRS_CAP (NP * NL)      // 32768 pairs per complex max
#define CHUNKS 512               // PAIRS_CAP / 64
#define K1 96                    // extended layer-1 K: 32 rb + 20 pt + 16 lt + pad

typedef __attribute__((ext_vector_type(8))) _Float16 h8;
typedef __attribute__((ext_vector_type(4))) float f4;

// ---------------------------------------------------------------------------
// Kernel A: fused prep (unchanged from R9).
//  blk 0..7: compaction -> packed records {dist,(pt<<16)|lt}; blk 8: zero acc;
//  blk 9..104: wt1e col k; blk 105..232: wt2t/wt3t transpose row k.
// ---------------------------------------------------------------------------
__global__ __launch_bounds__(256) void prep(
    const float* __restrict__ ppos, const float* __restrict__ lpos,
    const int* __restrict__ ptype_g, const int* __restrict__ ltype_g,
    const float* __restrict__ pemb, const float* __restrict__ lemb,
    const float* __restrict__ W1, const float* __restrict__ b1,
    const float* __restrict__ W2, const float* __restrict__ W3,
    uint2* __restrict__ rec, unsigned* __restrict__ cnt,
    _Float16* __restrict__ wt1e, _Float16* __restrict__ wt2t,
    _Float16* __restrict__ wt3t, float* __restrict__ acc)
{
  int blk = blockIdx.x, tid = threadIdx.x;

  if (blk < 8) {
    int b = blk;
    int w = tid >> 6, lane = tid & 63;
    __shared__ float slig[NL * 3];
    __shared__ int slt[NL];
    __shared__ unsigned wtot[4];

    if (tid < NL * 3) slig[tid] = lpos[b * NL * 3 + tid];
    if (tid < NL) slt[tid] = ltype_g[b * NL + tid];
    __syncthreads();

    const float* pp = ppos + (size_t)(b * NP + 2 * tid) * 3;
    float p0x = pp[0], p0y = pp[1], p0z = pp[2];
    float p1x = pp[3], p1y = pp[4], p1z = pp[5];
    unsigned pt0 = (unsigned)ptype_g[b * NP + 2 * tid];
    unsigned pt1 = (unsigned)ptype_g[b * NP + 2 * tid + 1];

    unsigned long long m0 = 0ull, m1 = 0ull;
    for (int l = 0; l < NL; ++l) {
      float qx = slig[3 * l + 0], qy = slig[3 * l + 1], qz = slig[3 * l + 2];
      float dx0 = p0x - qx, dy0 = p0y - qy, dz0 = p0z - qz;
      float dx1 = p1x - qx, dy1 = p1y - qy, dz1 = p1z - qz;
      bool v0 = sqrtf(dx0 * dx0 + dy0 * dy0 + dz0 * dz0) < 8.0f;
      bool v1 = sqrtf(dx1 * dx1 + dy1 * dy1 + dz1 * dz1) < 8.0f;
      m0 |= ((unsigned long long)v0) << l;
      m1 |= ((unsigned long long)v1) << l;
    }
    unsigned count = (unsigned)(__popcll(m0) + __popcll(m1));

    unsigned inc = count;
    #pragma unroll
    for (int d = 1; d < 64; d <<= 1) {
      unsigned v = __shfl_up(inc, d);
      if (lane >= d) inc += v;
    }
    if (lane == 63) wtot[w] = inc;
    __syncthreads();
    unsigned wbase = 0;
    for (int i = 0; i < w; ++i) wbase += wtot[i];
    unsigned base = wbase + inc - count;          // exclusive prefix
    if (tid == 255) cnt[b] = wbase + inc;

    uint2* dst = rec + (size_t)b * PAIRS_CAP;
    unsigned long long mm = m0;
    while (mm) {
      int l = __builtin_ctzll(mm); mm &= mm - 1ull;
      float dx = p0x - slig[3 * l], dy = p0y - slig[3 * l + 1], dz = p0z - slig[3 * l + 2];
      float d = sqrtf(dx * dx + dy * dy + dz * dz);
      dst[base++] = (uint2){__float_as_uint(d), (pt0 << 16) | (unsigned)slt[l]};
    }
    mm = m1;
    while (mm) {
      int l = __builtin_ctzll(mm); mm &= mm - 1ull;
      float dx = p1x - slig[3 * l], dy = p1y - slig[3 * l + 1], dz = p1z - slig[3 * l + 2];
      float d = sqrtf(dx * dx + dy * dy + dz * dz);
      dst[base++] = (uint2){__float_as_uint(d), (pt1 << 16) | (unsigned)slt[l]};
    }
    return;
  }

  if (blk == 8) {
    for (int i = tid; i < NB * NH; i += 256) acc[i] = 0.0f;
    return;
  }

  if (blk < 105) {
    int k = blk - 9;
    if (tid >= NH) return;
    int c = tid;
    float v;
    if (k < 32) {
      v = W1[(2 * NH + k) * NH + c];
    } else if (k < 52) {
      int t = k - 32;
      float s = b1[c];
      for (int j = 0; j < NH; ++j)
        s = fmaf(pemb[t * NH + j], W1[j * NH + c], s);
      v = s;
    } else if (k < 68) {
      int t = k - 52;
      float s = 0.0f;
      for (int j = 0; j < NH; ++j)
        s = fmaf(lemb[t * NH + j], W1[(NH + j) * NH + c], s);
      v = s;
    } else {
      v = 0.0f;
    }
    wt1e[c * K1 + k] = (_Float16)v;
    return;
  }

  {
    int k = blk - 105;
    if (tid >= NH) return;
    int c = tid;
    wt2t[c * NH + k] = (_Float16)W2[k * NH + c];
    wt3t[c * NH + k] = (_Float16)W3[k * NH + c];
    return;
  }
}

// ---------------------------------------------------------------------------
// Kernel B: MFMA pair MLP — R9 body with SINGLE 16KB in-place LDS tile.
// Occupancy lever: 256B/pair LDS -> 8 blocks/CU (32 waves, HW cap) vs R9's 5.
// Costs +3 barriers (read-complete fences before in-place writes); with 32
// waves resident the barrier drains are hidden by other blocks' work.
// launch_bounds(256,4): VGPR cap 128 (R9 measured 64 with this bound; R7's
// failure was the (256,6) bound squeezing VGPR to 40, not the single tile).
// Wave cg owns cols [32cg,32cg+32); 16x16x32_f16 MFMA, fp32 acc; XOR
// swizzle (half_idx ^= (row&7)<<3) -> conflict-free ds_read_b128.
// C/D layout per m89: row = 16m + (lane>>4)*4 + reg, col = 16n + (lane&15).
// ---------------------------------------------------------------------------
__device__ __forceinline__ int swz(int row, int col) {
  return row * NH + (col ^ ((row & 7) << 3));   // half-index swizzle
}

__global__ __launch_bounds__(256, 4) void pair_mlp(
    const _Float16* __restrict__ wt1e, const _Float16* __restrict__ wt2t,
    const _Float16* __restrict__ wt3t,
    const float* __restrict__ b2, const float* __restrict__ b3,
    const uint2* __restrict__ rec, const unsigned* __restrict__ cnt,
    float* __restrict__ accum)
{
  __shared__ _Float16 sS[NL * NH];   // 16 KB single tile, in-place per layer

  int tid = threadIdx.x;
  int cg = __builtin_amdgcn_readfirstlane(tid >> 6);
  int l  = tid & 63;
  int b     = blockIdx.x & 7;
  int chunk = blockIdx.x >> 3;

  unsigned total = cnt[b];
  if ((unsigned)(chunk * 64) >= total) return;

  int idx = chunk * 64 + l;
  int src = ((unsigned)idx < total) ? idx : 0;    // duplicate row 0 in tail
  uint2 rcd = rec[(size_t)b * PAIRS_CAP + src];   // ONE coalesced 8B load
  float dist = __uint_as_float(rcd.x);
  int pt = (int)(rcd.y >> 16), lt = (int)(rcd.y & 0xffffu);

  const float stepc = 8.0f / 31.0f;
  const float invw = 1.0f / (0.125f + 1e-8f);

  // --- build extended-A row l (0..31 rb | 32..51 pt-1hot | 52..67 lt-1hot
  // | 68..95 zero) into sS. Wave cg writes 16B chunks 3cg..3cg+2. -----------
  for (int jj = 0; jj < 3; ++jj) {
    int ch = 3 * cg + jj;                         // wave-uniform
    h8 v;
    #pragma unroll
    for (int i = 0; i < 8; ++i) {
      int c = ch * 8 + i;
      float x;
      if (c < 32) { float t = (dist - stepc * (float)c) * invw; x = __expf(-0.5f * t * t); }
      else if (c < 52) x = (c - 32 == pt) ? 1.0f : 0.0f;
      else if (c < 68) x = (c - 52 == lt) ? 1.0f : 0.0f;
      else x = 0.0f;
      v[i] = (_Float16)x;
    }
    *(h8*)&sS[swz(l, ch * 8)] = v;
  }
  __syncthreads();                                // bar 1: ext-A ready

  int col0 = cg * 32 + (l & 15);                  // n=0 column for this lane
  int krow = 8 * (l >> 4);                        // k sub-row for A/B frags
  int g4 = (l >> 4) * 4;                          // C-frag row group

  // --- layer 1: K=96, reads sS(ext-A), writes h1 in place ------------------
  {
    h8 B1[2][3];
    #pragma unroll
    for (int n = 0; n < 2; ++n)
      #pragma unroll
      for (int kk = 0; kk < 3; ++kk)
        B1[n][kk] = *(const h8*)&wt1e[(col0 + 16 * n) * K1 + 32 * kk + krow];

    f4 acc1[4][2];
    #pragma unroll
    for (int m = 0; m < 4; ++m)
      #pragma unroll
      for (int n = 0; n < 2; ++n)
        acc1[m][n] = (f4){0.0f, 0.0f, 0.0f, 0.0f};

    #pragma unroll
    for (int m = 0; m < 4; ++m) {
      int row = 16 * m + (l & 15);
      #pragma unroll
      for (int kk = 0; kk < 3; ++kk) {
        h8 a = *(const h8*)&sS[swz(row, 32 * kk + krow)];
        acc1[m][0] = __builtin_amdgcn_mfma_f32_16x16x32_f16(a, B1[0][kk], acc1[m][0], 0, 0, 0);
        acc1[m][1] = __builtin_amdgcn_mfma_f32_16x16x32_f16(a, B1[1][kk], acc1[m][1], 0, 0, 0);
      }
    }
    __syncthreads();                              // bar 2: all ext-A reads done
    #pragma unroll
    for (int m = 0; m < 4; ++m)
      #pragma unroll
      for (int n = 0; n < 2; ++n)
        #pragma unroll
        for (int r = 0; r < 4; ++r) {
          int row = 16 * m + g4 + r;
          sS[swz(row, cg * 32 + 16 * n + (l & 15))] =
              (_Float16)fmaxf(acc1[m][n][r], 0.0f);
        }
  }
  __syncthreads();                                // bar 3: h1 ready

  // --- layer 2: K=128, reads sS(h1), writes h2 in place --------------------
  {
    h8 B2[2][4];
    #pragma unroll
    for (int n = 0; n < 2; ++n)
      #pragma unroll
      for (int kk = 0; kk < 4; ++kk)
        B2[n][kk] = *(const h8*)&wt2t[(col0 + 16 * n) * NH + 32 * kk + krow];

    float bias0 = b2[col0], bias1 = b2[col0 + 16];
    f4 acc2[4][2];
    #pragma unroll
    for (int m = 0; m < 4; ++m) {
      acc2[m][0] = (f4){bias0, bias0, bias0, bias0};
      acc2[m][1] = (f4){bias1, bias1, bias1, bias1};
    }
    #pragma unroll
    for (int m = 0; m < 4; ++m) {
      int row = 16 * m + (l & 15);
      #pragma unroll
      for (int kk = 0; kk < 4; ++kk) {
        h8 a = *(const h8*)&sS[swz(row, 32 * kk + krow)];
        acc2[m][0] = __builtin_amdgcn_mfma_f32_16x16x32_f16(a, B2[0][kk], acc2[m][0], 0, 0, 0);
        acc2[m][1] = __builtin_amdgcn_mfma_f32_16x16x32_f16(a, B2[1][kk], acc2[m][1], 0, 0, 0);
      }
    }
    __syncthreads();                              // bar 4: all h1 reads done
    #pragma unroll
    for (int m = 0; m < 4; ++m)
      #pragma unroll
      for (int n = 0; n < 2; ++n)
        #pragma unroll
        for (int r = 0; r < 4; ++r) {
          int row = 16 * m + g4 + r;
          sS[swz(row, cg * 32 + 16 * n + (l & 15))] =
              (_Float16)fmaxf(acc2[m][n][r], 0.0f);
        }
  }
  __syncthreads();                                // bar 5: h2 ready

  // --- layer 3: K=128, reads sS(h2), masked column-sum -> atomics ----------
  {
    h8 B3[2][4];
    #pragma unroll
    for (int n = 0; n < 2; ++n)
      #pragma unroll
      for (int kk = 0; kk < 4; ++kk)
        B3[n][kk] = *(const h8*)&wt3t[(col0 + 16 * n) * NH + 32 * kk + krow];

    float bias0 = b3[col0], bias1 = b3[col0 + 16];
    f4 acc3[4][2];
    #pragma unroll
    for (int m = 0; m < 4; ++m) {
      acc3[m][0] = (f4){bias0, bias0, bias0, bias0};
      acc3[m][1] = (f4){bias1, bias1, bias1, bias1};
    }
    #pragma unroll
    for (int m = 0; m < 4; ++m) {
      int row = 16 * m + (l & 15);
      #pragma unroll
      for (int kk = 0; kk < 4; ++kk) {
        h8 a = *(const h8*)&sS[swz(row, 32 * kk + krow)];
        acc3[m][0] = __builtin_amdgcn_mfma_f32_16x16x32_f16(a, B3[0][kk], acc3[m][0], 0, 0, 0);
        acc3[m][1] = __builtin_amdgcn_mfma_f32_16x16x32_f16(a, B3[1][kk], acc3[m][1], 0, 0, 0);
      }
    }

    int rem = (int)total - chunk * 64;            // rows < rem are valid
    float cs0 = 0.0f, cs1 = 0.0f;
    #pragma unroll
    for (int m = 0; m < 4; ++m)
      #pragma unroll
      for (int r = 0; r < 4; ++r) {
        int row = 16 * m + g4 + r;
        bool ok = row < rem;
        cs0 += ok ? fmaxf(acc3[m][0][r], 0.0f) : 0.0f;
        cs1 += ok ? fmaxf(acc3[m][1][r], 0.0f) : 0.0f;
      }
    cs0 += __shfl_xor(cs0, 16); cs0 += __shfl_xor(cs0, 32);
    cs1 += __shfl_xor(cs1, 16); cs1 += __shfl_xor(cs1, 32);
    int g = l >> 4;
    if (g == 0)      atomicAdd(&accum[b * NH + cg * 32 + (l & 15)], cs0);
    else if (g == 1) atomicAdd(&accum[b * NH + cg * 32 + 16 + (l & 15)], cs1);
  }
}

// ---------------------------------------------------------------------------
// Kernel C: scoring head (unchanged from R9).
// ---------------------------------------------------------------------------
__global__ __launch_bounds__(128) void score_head(
    const float* __restrict__ acc, const unsigned* __restrict__ cnt,
    const float* __restrict__ Wr1, const float* __restrict__ br1,
    const float* __restrict__ Wr2, const float* __restrict__ br2,
    float* __restrict__ out)
{
  int b = blockIdx.x;
  int tid = threadIdx.x;
  __shared__ float sr[NH];
  __shared__ float wsum[2];
  unsigned c = cnt[b];
  float denom = fmaxf((float)c, 1.0f);
  sr[tid] = acc[b * NH + tid] / denom;
  __syncthreads();
  float s = br1[tid];
  for (int k = 0; k < NH; ++k)
    s = fmaf(sr[k], Wr1[k * NH + tid], s);
  float v = fmaxf(s, 0.0f) * Wr2[tid];
  #pragma unroll
  for (int d = 1; d < 64; d <<= 1) v += __shfl_xor(v, d);
  if ((tid & 63) == 0) wsum[tid >> 6] = v;
  __syncthreads();
  if (tid == 0)
    out[b] = (c > 0) ? (wsum[0] + wsum[1] + br2[0]) : 0.0f;
}

// ---------------------------------------------------------------------------
extern "C" void kernel_launch(void* const* d_in, const int* in_sizes, int n_in,
                              void* d_out, int out_size, void* d_ws, size_t ws_size,
                              hipStream_t stream)
{
  const float* ppos = (const float*)d_in[0];
  const float* lpos = (const float*)d_in[1];
  const float* pemb = (const float*)d_in[2];
  const float* lemb = (const float*)d_in[3];
  const float* W1   = (const float*)d_in[4];
  const float* b1   = (const float*)d_in[5];
  const float* W2   = (const float*)d_in[6];
  const float* b2   = (const float*)d_in[7];
  const float* W3   = (const float*)d_in[8];
  const float* b3   = (const float*)d_in[9];
  const float* Wr1  = (const float*)d_in[10];
  const float* br1  = (const float*)d_in[11];
  const float* Wr2  = (const float*)d_in[12];
  const float* br2  = (const float*)d_in[13];
  const int*   ptyp = (const int*)d_in[14];
  const int*   ltyp = (const int*)d_in[15];
  // d_in[16], d_in[17] (batch indices) unused: batches contiguous & uniform.

  float* ws  = (float*)d_ws;
  float* acc = ws;                          // 1024 f
  unsigned* cnt = (unsigned*)(ws + 1024);   // 8 u32 (pad to 1032)
  uint2* rec = (uint2*)(ws + 1032);         // 8*32768*8B = 2 MB (524288 f)
  _Float16* wt1e = (_Float16*)(ws + 1032 + 524288);                // 128*96 h
  _Float16* wt2t = (_Float16*)(ws + 1032 + 524288 + 6144);         // 128*128 h
  _Float16* wt3t = (_Float16*)(ws + 1032 + 524288 + 6144 + 8192);  // 128*128 h

  prep<<<233, 256, 0, stream>>>(ppos, lpos, ptyp, ltyp, pemb, lemb,
                                W1, b1, W2, W3,
                                rec, cnt, wt1e, wt2t, wt3t, acc);
  pair_mlp<<<NB * CHUNKS, 256, 0, stream>>>(wt1e, wt2t, wt3t, b2, b3,
                                            rec, cnt, acc);
  score_head<<<NB, 128, 0, stream>>>(acc, cnt, Wr1, br1, Wr2, br2, (float*)d_out);
}